// Round 10
// baseline (158.052 us; speedup 1.0000x reference)
//
#include <hip/hip_runtime.h>

#define N_NODES 50001
#define DIM 128
#define GEMM_BLOCKS 782                // ceil(N_NODES / 64): 4 waves x 16 rows per block
#define CAP 64                         // slot capacity per node (avg deg ~12, P(>=64)~1e-30)
#define NB 196                         // buckets = dst>>8  (50000>>8 = 195)
#define SC 512                         // capacity per (bucket, replica) sub-list
#define ZB 7                           // prep zero blocks: 7*256 >= NB*8

typedef __attribute__((ext_vector_type(8))) short short8v;   // 8 bf16 (MFMA A/B frag)
typedef __attribute__((ext_vector_type(4))) float f32x4;     // MFMA C/D frag

__device__ __forceinline__ ushort f2bf(float f) {
    unsigned u = __float_as_uint(f);
    unsigned r = (u + 0x7FFF + ((u >> 16) & 1)) >> 16;   // round-to-nearest-even
    return (ushort)r;
}

// ---------------- prep: [zero bucket counters | transpose W -> wt (bf16 [n][k])] ----------
__global__ void prep_kernel(int* __restrict__ bcnt, const float* __restrict__ Wg,
                            ushort* __restrict__ wt) {
    __shared__ float tile[32][36];
    const int t = threadIdx.x;
    if (blockIdx.x < ZB) {
        int i = blockIdx.x * 256 + t;
        if (i < NB * 8) bcnt[i] = 0;
        return;
    }
    const int b2 = blockIdx.x - ZB;       // 0..15
    const int bk = b2 >> 2;               // k-tile
    const int bn = b2 & 3;                // n-tile
    {
        int k = bk * 32 + (t >> 3);
        int n = bn * 32 + (t & 7) * 4;
        float4 v = *(const float4*)&Wg[(size_t)k * DIM + n];
        tile[t >> 3][(t & 7) * 4 + 0] = v.x;
        tile[t >> 3][(t & 7) * 4 + 1] = v.y;
        tile[t >> 3][(t & 7) * 4 + 2] = v.z;
        tile[t >> 3][(t & 7) * 4 + 3] = v.w;
    }
    __syncthreads();
    {
        int n = bn * 32 + (t >> 3);
        int k = bk * 32 + (t & 7) * 4;
        ushort4 w4;
        w4.x = f2bf(tile[(t & 7) * 4 + 0][t >> 3]);
        w4.y = f2bf(tile[(t & 7) * 4 + 1][t >> 3]);
        w4.z = f2bf(tile[(t & 7) * 4 + 2][t >> 3]);
        w4.w = f2bf(tile[(t & 7) * 4 + 3][t >> 3]);
        *(ushort4*)&wt[(size_t)n * DIM + k] = w4;
    }
}

// ---------------- fused: [MFMA gemm (first) | level-1 binning (XCD-local append)] --------
// gemm: h16 = bf16(x @ W), x = W_embed with row 0 zeroed. Wave = 16 rows x 128 cols.
// bin1: bucket = dst>>8, replica r = blockIdx&7 (~XCD id via round-robin dispatch —
//       locality heuristic only). entry = src | (dst&255)<<16.
__launch_bounds__(256)
__global__ void gemm_fill_kernel(const float* __restrict__ X, const ushort* __restrict__ wt,
                                 ushort* __restrict__ h16,
                                 const int* __restrict__ src, const int* __restrict__ dst,
                                 int E, int* __restrict__ bcnt, unsigned* __restrict__ bkt) {
    const int bid = blockIdx.x;
    if (bid >= GEMM_BLOCKS) {
        const int fid = bid - GEMM_BLOCKS;
        int e = fid * 256 + threadIdx.x;
        if (e < E) {
            int d = dst[e];
            int s = src[e];
            int b = d >> 8;
            int r = bid & 7;
            int pos = atomicAdd(&bcnt[(b << 3) + r], 1);
            if (pos < SC)
                bkt[(((b << 3) + r) << 9) + pos] = (unsigned)s | ((unsigned)(d & 255) << 16);
        }
        return;
    }
    const int vb   = bid;
    const int l    = threadIdx.x & 63;
    const int wave = threadIdx.x >> 6;
    const int m0   = vb * 64 + wave * 16;
    const int lm   = l & 15;          // A row / D col index
    const int lg   = l >> 4;          // k-group

    const int arow  = m0 + lm;
    const bool aok  = (arow > 0) && (arow < N_NODES);   // row 0 forced to zero
    const int koff0 = lg * 8;

    f32x4 acc[8];
#pragma unroll
    for (int ct = 0; ct < 8; ++ct) acc[ct] = (f32x4){0.f, 0.f, 0.f, 0.f};

#pragma unroll
    for (int kci = 0; kci < 4; ++kci) {
        const int kc = kci * 32;
        // A frag: X[arow][kc + koff0 + 0..7] fp32 -> bf16 (same (g,j)->k bijection as B)
        float4 v0 = make_float4(0.f, 0.f, 0.f, 0.f), v1 = v0;
        if (aok) {
            const float* xp = &X[(size_t)arow * DIM + kc + koff0];
            v0 = *(const float4*)xp;
            v1 = *(const float4*)(xp + 4);
        }
        short8v a;
        a[0] = (short)f2bf(v0.x); a[1] = (short)f2bf(v0.y);
        a[2] = (short)f2bf(v0.z); a[3] = (short)f2bf(v0.w);
        a[4] = (short)f2bf(v1.x); a[5] = (short)f2bf(v1.y);
        a[6] = (short)f2bf(v1.z); a[7] = (short)f2bf(v1.w);
#pragma unroll
        for (int ct = 0; ct < 8; ++ct) {
            // B frag: wt[(ct*16 + lm)][kc + koff0 + 0..7] — 16B vector load, cache-resident
            short8v b = *(const short8v*)&wt[(size_t)(ct * 16 + lm) * DIM + kc + koff0];
            acc[ct] = __builtin_amdgcn_mfma_f32_16x16x32_bf16(a, b, acc[ct], 0, 0, 0);
        }
    }

    // D: row = m0 + lg*4 + r, col = ct*16 + lm
#pragma unroll
    for (int r = 0; r < 4; ++r) {
        int row = m0 + lg * 4 + r;
        if (row < N_NODES) {
            ushort* hp = &h16[(size_t)row * DIM + lm];
#pragma unroll
            for (int ct = 0; ct < 8; ++ct) hp[ct * 16] = f2bf(acc[ct][r]);
        }
    }
}

// ---------------- level-2: per-bucket LDS binning -> slot rows + deg (all streaming) ------
__launch_bounds__(256)
__global__ void bin_kernel(const int* __restrict__ bcnt, const unsigned* __restrict__ bkt,
                           ushort* __restrict__ slot, int* __restrict__ deg) {
    __shared__ __align__(16) ushort lslot[256 * CAP];   // 32 KB
    __shared__ int ldeg[256];
    const int t = threadIdx.x;
    const int b = blockIdx.x;
    ldeg[t] = 0;
    __syncthreads();

    for (int r = 0; r < 8; ++r) {
        const int cnt = min(bcnt[(b << 3) + r], SC);
        const unsigned* bp = &bkt[((b << 3) + r) << 9];
        for (int i = t; i < cnt; i += 256) {
            unsigned en = bp[i];
            int dlow = (en >> 16) & 255;
            int pos = atomicAdd(&ldeg[dlow], 1);
            if (pos < CAP) lslot[dlow * CAP + pos] = (ushort)(en & 0xFFFFu);
        }
    }
    __syncthreads();

    const int node = b * 256 + t;
    if (node < N_NODES) deg[node] = ldeg[t];
    // stream 32 KB of slot rows (uninitialized tails beyond ldeg are never read)
    const uint4* ls4 = (const uint4*)lslot;
    uint4* gs4 = (uint4*)&slot[(size_t)b * 256 * CAP];
#pragma unroll
    for (int k = 0; k < 8; ++k) gs4[k * 256 + t] = ls4[k * 256 + t];
}

// ---------------- pull: out[n] = dis_n*(sum_e dis_s*h[s] + dis_n*h[n]) + b ----------
// One wave per node; quarter-wave (16 lanes x 16B) per edge -> 4 edges in flight.
__launch_bounds__(256)
__global__ void pull_kernel(const int* __restrict__ deg, const ushort* __restrict__ slot,
                            const ushort* __restrict__ h16,
                            const float* __restrict__ b, float* __restrict__ out) {
    const int tid  = threadIdx.x;
    const int lane = tid & 63;
    const int g    = lane >> 4;     // edge slot group 0..3
    const int c    = lane & 15;     // col slot: bf16 cols c*8 .. c*8+7
    const int n    = blockIdx.x * 4 + (tid >> 6);
    if (n >= N_NODES) return;

    const int dn_i = deg[n];
    const int end  = min(dn_i, CAP);
    const ushort* sp = &slot[(size_t)n * CAP];

    float ac[8];
#pragma unroll
    for (int j = 0; j < 8; ++j) ac[j] = 0.f;

    int e = g;
    while (e + 4 < end) {           // 2 edges per group per iter
        int s0 = sp[e];
        int s1 = sp[e + 4];
        float d0 = rsqrtf(1.0f + (float)deg[s0]);
        float d1 = rsqrtf(1.0f + (float)deg[s1]);
        uint4 u0 = *(const uint4*)&h16[(size_t)s0 * DIM + c * 8];
        uint4 u1 = *(const uint4*)&h16[(size_t)s1 * DIM + c * 8];
        const unsigned w0[4] = {u0.x, u0.y, u0.z, u0.w};
        const unsigned w1[4] = {u1.x, u1.y, u1.z, u1.w};
#pragma unroll
        for (int p = 0; p < 4; ++p) {
            ac[2*p]   += d0 * __uint_as_float(w0[p] << 16)
                       + d1 * __uint_as_float(w1[p] << 16);
            ac[2*p+1] += d0 * __uint_as_float(w0[p] & 0xFFFF0000u)
                       + d1 * __uint_as_float(w1[p] & 0xFFFF0000u);
        }
        e += 8;
    }
    while (e < end) {
        int s = sp[e];
        float d = rsqrtf(1.0f + (float)deg[s]);
        uint4 u = *(const uint4*)&h16[(size_t)s * DIM + c * 8];
        const unsigned w[4] = {u.x, u.y, u.z, u.w};
#pragma unroll
        for (int p = 0; p < 4; ++p) {
            ac[2*p]   += d * __uint_as_float(w[p] << 16);
            ac[2*p+1] += d * __uint_as_float(w[p] & 0xFFFF0000u);
        }
        e += 4;
    }

    // combine the 4 edge-slot partials (same cols in every group)
#pragma unroll
    for (int j = 0; j < 8; ++j) {
        ac[j] += __shfl_xor(ac[j], 16, 64);
        ac[j] += __shfl_xor(ac[j], 32, 64);
    }

    if (g == 0) {
        const float dn = rsqrtf(1.0f + (float)dn_i);
        uint4 us = *(const uint4*)&h16[(size_t)n * DIM + c * 8];   // self row (bf16)
        const unsigned ws[4] = {us.x, us.y, us.z, us.w};
        float r[8];
#pragma unroll
        for (int p = 0; p < 4; ++p) {
            r[2*p]   = ac[2*p]   + dn * __uint_as_float(ws[p] << 16);
            r[2*p+1] = ac[2*p+1] + dn * __uint_as_float(ws[p] & 0xFFFF0000u);
        }
        float* op = &out[(size_t)n * DIM + c * 8];
        const float* bp = &b[c * 8];
        float4 o0, o1;
        o0.x = dn * r[0] + bp[0]; o0.y = dn * r[1] + bp[1];
        o0.z = dn * r[2] + bp[2]; o0.w = dn * r[3] + bp[3];
        o1.x = dn * r[4] + bp[4]; o1.y = dn * r[5] + bp[5];
        o1.z = dn * r[6] + bp[6]; o1.w = dn * r[7] + bp[7];
        *(float4*)op = o0;
        *(float4*)(op + 4) = o1;
    }
}

extern "C" void kernel_launch(void* const* d_in, const int* in_sizes, int n_in,
                              void* d_out, int out_size, void* d_ws, size_t ws_size,
                              hipStream_t stream) {
    const float* W_embed = (const float*)d_in[0];
    const float* W_gcn   = (const float*)d_in[1];
    const float* b_gcn   = (const float*)d_in[2];
    const int*   edges   = (const int*)d_in[3];
    const int E = in_sizes[3] / 2;
    const int* src = edges;
    const int* dst = edges + E;

    float* out = (float*)d_out;
    char*  ws  = (char*)d_ws;
    int*      bcnt = (int*)ws;                      // NB*8 ints (6.3 KB)   @ 0
    ushort*   wt   = (ushort*)(ws + 16384);         // 128x128 bf16 (32 KB) @ 16 KB
    unsigned* bkt  = (unsigned*)(ws + 65536);       // NB*8*SC uint (3.2MB) @ 64 KB
    ushort*   slot = (ushort*)(ws + 3407872);       // NB*256*CAP ushort (6.4MB)
    int*      deg  = (int*)(ws + 9961472);          // N ints
    ushort*   h16  = (ushort*)(ws + 10485760);      // N*D bf16 (12.8 MB)

    const int fill_blocks = (E + 255) / 256;        // 2344

    prep_kernel<<<ZB + 16, 256, 0, stream>>>(bcnt, W_gcn, wt);
    gemm_fill_kernel<<<GEMM_BLOCKS + fill_blocks, 256, 0, stream>>>(
        W_embed, wt, h16, src, dst, E, bcnt, bkt);
    bin_kernel<<<NB, 256, 0, stream>>>(bcnt, bkt, slot, deg);
    pull_kernel<<<(N_NODES + 3) / 4, 256, 0, stream>>>(deg, slot, h16, b_gcn, out);
}

// Round 11
// 99.108 us; speedup vs baseline: 1.5948x; 1.5948x over previous
//
#include <hip/hip_runtime.h>

#define N_NODES 50001
#define DIM 128
#define GEMM_BLOCKS 782                // ceil(N_NODES / 64): 4 waves x 16 rows per block
#define NREP 8                         // one replica per XCD
#define RCAP 16                        // per-(replica,node) capacity; Poisson mean 1.5
#define ZBLK 391                       // zero blocks: 8*50001 ints = 100002 uint4 / 256

typedef __attribute__((ext_vector_type(8))) short short8v;   // 8 bf16 (MFMA A/B frag)
typedef __attribute__((ext_vector_type(4))) float f32x4;     // MFMA C/D frag

__device__ __forceinline__ ushort f2bf(float f) {
    unsigned u = __float_as_uint(f);
    unsigned r = (u + 0x7FFF + ((u >> 16) & 1)) >> 16;   // round-to-nearest-even
    return (ushort)r;
}

// ---------------- prep: [zero degr | transpose W (fp32) -> wt (bf16 [n][k])] ----------
__global__ void prep_kernel(int* __restrict__ degr, const float* __restrict__ Wg,
                            ushort* __restrict__ wt) {
    __shared__ float tile[32][36];
    const int t = threadIdx.x;
    if (blockIdx.x < ZBLK) {
        int i = blockIdx.x * 256 + t;
        if (i < (NREP * N_NODES + 3) / 4)
            ((uint4*)degr)[i] = make_uint4(0, 0, 0, 0);
        return;
    }
    const int b2 = blockIdx.x - ZBLK;     // 0..15
    const int bk = b2 >> 2;               // k-tile
    const int bn = b2 & 3;                // n-tile
    {
        int k = bk * 32 + (t >> 3);
        int n = bn * 32 + (t & 7) * 4;
        float4 v = *(const float4*)&Wg[(size_t)k * DIM + n];
        tile[t >> 3][(t & 7) * 4 + 0] = v.x;
        tile[t >> 3][(t & 7) * 4 + 1] = v.y;
        tile[t >> 3][(t & 7) * 4 + 2] = v.z;
        tile[t >> 3][(t & 7) * 4 + 3] = v.w;
    }
    __syncthreads();
    {
        int n = bn * 32 + (t >> 3);
        int k = bk * 32 + (t & 7) * 4;
        ushort4 w4;
        w4.x = f2bf(tile[(t & 7) * 4 + 0][t >> 3]);
        w4.y = f2bf(tile[(t & 7) * 4 + 1][t >> 3]);
        w4.z = f2bf(tile[(t & 7) * 4 + 2][t >> 3]);
        w4.w = f2bf(tile[(t & 7) * 4 + 3][t >> 3]);
        *(ushort4*)&wt[(size_t)n * DIM + k] = w4;
    }
}

// ------- fused: [MFMA gemm (first) | fill into XCD-local replica slot arrays] -----------
// fill: r = blockIdx&7 (~XCD via round-robin dispatch; locality heuristic only).
//       pos = degr[r][dst]++; slot[r][dst][pos] = src.  One-XCD-writer lines, ~1.5 ops/ctr.
// gemm: h16 = bf16(x @ W), x = W_embed with row 0 zeroed. Wave = 16 rows x 128 cols.
__launch_bounds__(256)
__global__ void gemm_fill_kernel(const float* __restrict__ X, const ushort* __restrict__ wt,
                                 ushort* __restrict__ h16,
                                 const int* __restrict__ src, const int* __restrict__ dst,
                                 int E, int* __restrict__ degr, ushort* __restrict__ slot) {
    const int bid = blockIdx.x;
    if (bid >= GEMM_BLOCKS) {
        const int fid = bid - GEMM_BLOCKS;
        int e = fid * 256 + threadIdx.x;
        if (e < E) {
            int d = dst[e];
            int s = src[e];
            int r = bid & 7;
            int idx = r * N_NODES + d;
            int pos = atomicAdd(&degr[idx], 1);
            if (pos < RCAP) slot[(size_t)idx * RCAP + pos] = (ushort)s;
        }
        return;
    }
    const int vb   = bid;
    const int l    = threadIdx.x & 63;
    const int wave = threadIdx.x >> 6;
    const int m0   = vb * 64 + wave * 16;
    const int lm   = l & 15;          // A row / D col index
    const int lg   = l >> 4;          // k-group

    const int arow  = m0 + lm;
    const bool aok  = (arow > 0) && (arow < N_NODES);   // row 0 forced to zero
    const int koff0 = lg * 8;

    f32x4 acc[8];
#pragma unroll
    for (int ct = 0; ct < 8; ++ct) acc[ct] = (f32x4){0.f, 0.f, 0.f, 0.f};

#pragma unroll
    for (int kci = 0; kci < 4; ++kci) {
        const int kc = kci * 32;
        // A frag: X[arow][kc + koff0 + 0..7] fp32 -> bf16 (same (g,j)->k bijection as B)
        float4 v0 = make_float4(0.f, 0.f, 0.f, 0.f), v1 = v0;
        if (aok) {
            const float* xp = &X[(size_t)arow * DIM + kc + koff0];
            v0 = *(const float4*)xp;
            v1 = *(const float4*)(xp + 4);
        }
        short8v a;
        a[0] = (short)f2bf(v0.x); a[1] = (short)f2bf(v0.y);
        a[2] = (short)f2bf(v0.z); a[3] = (short)f2bf(v0.w);
        a[4] = (short)f2bf(v1.x); a[5] = (short)f2bf(v1.y);
        a[6] = (short)f2bf(v1.z); a[7] = (short)f2bf(v1.w);
#pragma unroll
        for (int ct = 0; ct < 8; ++ct) {
            // B frag: wt[(ct*16 + lm)][kc + koff0 + 0..7] — 16B vector load, cache-resident
            short8v b = *(const short8v*)&wt[(size_t)(ct * 16 + lm) * DIM + kc + koff0];
            acc[ct] = __builtin_amdgcn_mfma_f32_16x16x32_bf16(a, b, acc[ct], 0, 0, 0);
        }
    }

    // D: row = m0 + lg*4 + r, col = ct*16 + lm
#pragma unroll
    for (int r = 0; r < 4; ++r) {
        int row = m0 + lg * 4 + r;
        if (row < N_NODES) {
            ushort* hp = &h16[(size_t)row * DIM + lm];
#pragma unroll
            for (int ct = 0; ct < 8; ++ct) hp[ct * 16] = f2bf(acc[ct][r]);
        }
    }
}

// ---------------- sumdeg: dis[n] = rsqrt(1 + sum_r degr[r][n]) ----------------
__global__ void sumdeg_kernel(const int* __restrict__ degr, float* __restrict__ dis) {
    const int n = blockIdx.x * 256 + threadIdx.x;
    if (n >= N_NODES) return;
    int s = 0;
#pragma unroll
    for (int r = 0; r < NREP; ++r) s += degr[r * N_NODES + n];
    dis[n] = rsqrtf(1.0f + (float)s);
}

// ---------------- pull: out[n] = dis_n*(sum_e dis_s*h[s] + dis_n*h[n]) + b ----------
// One wave per node; quarter-wave group g handles replicas {g, g+4}.
__launch_bounds__(256)
__global__ void pull_kernel(const int* __restrict__ degr, const ushort* __restrict__ slot,
                            const ushort* __restrict__ h16, const float* __restrict__ dis,
                            const float* __restrict__ b, float* __restrict__ out) {
    const int tid  = threadIdx.x;
    const int lane = tid & 63;
    const int g    = lane >> 4;     // replica group 0..3
    const int c    = lane & 15;     // col slot: bf16 cols c*8 .. c*8+7
    const int n    = blockIdx.x * 4 + (tid >> 6);
    if (n >= N_NODES) return;

    float ac[8];
#pragma unroll
    for (int j = 0; j < 8; ++j) ac[j] = 0.f;

#pragma unroll
    for (int rr = 0; rr < 2; ++rr) {
        const int idx = (g + rr * 4) * N_NODES + n;
        const int cnt = min(degr[idx], RCAP);
        const ushort* sp = &slot[(size_t)idx * RCAP];
        for (int e = 0; e < cnt; ++e) {
            int s = sp[e];
            float d = dis[s];
            uint4 u = *(const uint4*)&h16[(size_t)s * DIM + c * 8];
            const unsigned w[4] = {u.x, u.y, u.z, u.w};
#pragma unroll
            for (int p = 0; p < 4; ++p) {
                ac[2*p]   += d * __uint_as_float(w[p] << 16);
                ac[2*p+1] += d * __uint_as_float(w[p] & 0xFFFF0000u);
            }
        }
    }

    // combine the 4 replica-group partials (same cols in every group)
#pragma unroll
    for (int j = 0; j < 8; ++j) {
        ac[j] += __shfl_xor(ac[j], 16, 64);
        ac[j] += __shfl_xor(ac[j], 32, 64);
    }

    if (g == 0) {
        const float dn = dis[n];
        uint4 us = *(const uint4*)&h16[(size_t)n * DIM + c * 8];   // self row (bf16)
        const unsigned ws[4] = {us.x, us.y, us.z, us.w};
        float r[8];
#pragma unroll
        for (int p = 0; p < 4; ++p) {
            r[2*p]   = ac[2*p]   + dn * __uint_as_float(ws[p] << 16);
            r[2*p+1] = ac[2*p+1] + dn * __uint_as_float(ws[p] & 0xFFFF0000u);
        }
        float* op = &out[(size_t)n * DIM + c * 8];
        const float* bp = &b[c * 8];
        float4 o0, o1;
        o0.x = dn * r[0] + bp[0]; o0.y = dn * r[1] + bp[1];
        o0.z = dn * r[2] + bp[2]; o0.w = dn * r[3] + bp[3];
        o1.x = dn * r[4] + bp[4]; o1.y = dn * r[5] + bp[5];
        o1.z = dn * r[6] + bp[6]; o1.w = dn * r[7] + bp[7];
        *(float4*)op = o0;
        *(float4*)(op + 4) = o1;
    }
}

extern "C" void kernel_launch(void* const* d_in, const int* in_sizes, int n_in,
                              void* d_out, int out_size, void* d_ws, size_t ws_size,
                              hipStream_t stream) {
    const float* W_embed = (const float*)d_in[0];
    const float* W_gcn   = (const float*)d_in[1];
    const float* b_gcn   = (const float*)d_in[2];
    const int*   edges   = (const int*)d_in[3];
    const int E = in_sizes[3] / 2;
    const int* src = edges;
    const int* dst = edges + E;

    float* out = (float*)d_out;
    char*  ws  = (char*)d_ws;
    int*    degr = (int*)ws;                     // 8*N ints (1.6 MB)      @ 0
    ushort* wt   = (ushort*)(ws + 0x200000);     // 128x128 bf16 (32 KB)   @ 2 MB
    float*  dis  = (float*)(ws + 0x210000);      // N floats (200 KB)      @ 2.06 MB
    ushort* slot = (ushort*)(ws + 0x300000);     // 8*N*16 ushort (12.8MB) @ 3 MB
    ushort* h16  = (ushort*)(ws + 0x1000000);    // N*D bf16 (12.8 MB)     @ 16 MB

    const int fill_blocks = (E + 255) / 256;     // 2344

    prep_kernel<<<ZBLK + 16, 256, 0, stream>>>(degr, W_gcn, wt);
    gemm_fill_kernel<<<GEMM_BLOCKS + fill_blocks, 256, 0, stream>>>(
        W_embed, wt, h16, src, dst, E, degr, slot);
    sumdeg_kernel<<<(N_NODES + 255) / 256, 256, 0, stream>>>(degr, dis);
    pull_kernel<<<(N_NODES + 3) / 4, 256, 0, stream>>>(degr, slot, h16, dis, b_gcn, out);
}

// Round 12
// 73.047 us; speedup vs baseline: 2.1637x; 1.3568x over previous
//
#include <hip/hip_runtime.h>

#define N_NODES 50001
#define DIM 128
#define GEMM_BLOCKS 782                // ceil(N_NODES / 64): 4 waves x 16 rows per block
#define CAP 64                         // slot capacity per node
#define NB 196                         // buckets = dst>>8
#define FILLB 293                      // fill blocks
#define EPB 2048                       // edges per fill block (293*2048 >= 600000)
#define BCAP 40                        // per-(block,bucket) LDS capacity (mean 10.45)
#define GCAP 3584                      // per-bucket global capacity (mean 3061, sigma 55)
#define OCAP 8192                      // overflow list capacity

typedef __attribute__((ext_vector_type(8))) short short8v;   // 8 bf16 (MFMA A/B frag)
typedef __attribute__((ext_vector_type(4))) float f32x4;     // MFMA C/D frag

__device__ __forceinline__ ushort f2bf(float f) {
    unsigned u = __float_as_uint(f);
    unsigned r = (u + 0x7FFF + ((u >> 16) & 1)) >> 16;   // round-to-nearest-even
    return (ushort)r;
}

// ---------------- prep: [zero counters | transpose W (fp32) -> wt (bf16 [n][k])] ----------
__global__ void prep_kernel(int* __restrict__ gcntp, int* __restrict__ ocnt,
                            const float* __restrict__ Wg, ushort* __restrict__ wt) {
    __shared__ float tile[32][36];
    const int t = threadIdx.x;
    if (blockIdx.x == 0) {
        for (int i = t; i < NB * 16; i += 256) gcntp[i] = 0;
        if (t == 0) *ocnt = 0;
        return;
    }
    const int b2 = blockIdx.x - 1;        // 0..15
    const int bk = b2 >> 2;               // k-tile
    const int bn = b2 & 3;                // n-tile
    {
        int k = bk * 32 + (t >> 3);
        int n = bn * 32 + (t & 7) * 4;
        float4 v = *(const float4*)&Wg[(size_t)k * DIM + n];
        tile[t >> 3][(t & 7) * 4 + 0] = v.x;
        tile[t >> 3][(t & 7) * 4 + 1] = v.y;
        tile[t >> 3][(t & 7) * 4 + 2] = v.z;
        tile[t >> 3][(t & 7) * 4 + 3] = v.w;
    }
    __syncthreads();
    {
        int n = bn * 32 + (t >> 3);
        int k = bk * 32 + (t & 7) * 4;
        ushort4 w4;
        w4.x = f2bf(tile[(t & 7) * 4 + 0][t >> 3]);
        w4.y = f2bf(tile[(t & 7) * 4 + 1][t >> 3]);
        w4.z = f2bf(tile[(t & 7) * 4 + 2][t >> 3]);
        w4.w = f2bf(tile[(t & 7) * 4 + 3][t >> 3]);
        *(ushort4*)&wt[(size_t)n * DIM + k] = w4;
    }
}

// -------- fused: [MFMA gemm (first) | level-1: LDS bin 2048 edges -> bucket-run flush] ----
// entry = src | (dst&255)<<16  (| b<<24 in the overflow list)
__launch_bounds__(256)
__global__ void gemm_fill_kernel(const float* __restrict__ X, const ushort* __restrict__ wt,
                                 ushort* __restrict__ h16,
                                 const int* __restrict__ src, const int* __restrict__ dst,
                                 int E, int* __restrict__ gcntp, int* __restrict__ gbkt,
                                 int* __restrict__ ocnt, int* __restrict__ obkt) {
    __shared__ int lcnt[NB];
    __shared__ int lbkt[NB * BCAP];      // ~31 KB
    const int bid = blockIdx.x;
    const int t   = threadIdx.x;
    if (bid >= GEMM_BLOCKS) {
        const int fid = bid - GEMM_BLOCKS;
        for (int i = t; i < NB; i += 256) lcnt[i] = 0;
        __syncthreads();
        const int e0 = fid * EPB;
        const int e1 = min(e0 + EPB, E);
        for (int e = e0 + t; e < e1; e += 256) {
            int d = dst[e];
            int s = src[e];
            int b = d >> 8;
            unsigned en = (unsigned)s | ((unsigned)(d & 255) << 16);
            int pos = atomicAdd(&lcnt[b], 1);
            if (pos < BCAP) lbkt[b * BCAP + pos] = (int)en;
            else {
                int op = atomicAdd(ocnt, 1);
                if (op < OCAP) obkt[op] = (int)(en | ((unsigned)b << 24));
            }
        }
        __syncthreads();
        if (t < NB) {
            int c = min(lcnt[t], BCAP);
            if (c > 0) {
                int gpos = atomicAdd(&gcntp[t * 16], c);
                int* gp = &gbkt[t * GCAP];
                for (int i = 0; i < c; ++i) {
                    int g = gpos + i;
                    if (g < GCAP) gp[g] = lbkt[t * BCAP + i];
                    else {
                        int op = atomicAdd(ocnt, 1);
                        if (op < OCAP)
                            obkt[op] = (int)((unsigned)lbkt[t * BCAP + i] | ((unsigned)t << 24));
                    }
                }
            }
        }
        return;
    }
    const int vb   = bid;
    const int l    = t & 63;
    const int wave = t >> 6;
    const int m0   = vb * 64 + wave * 16;
    const int lm   = l & 15;          // A row / D col index
    const int lg   = l >> 4;          // k-group

    const int arow  = m0 + lm;
    const bool aok  = (arow > 0) && (arow < N_NODES);   // row 0 forced to zero
    const int koff0 = lg * 8;

    f32x4 acc[8];
#pragma unroll
    for (int ct = 0; ct < 8; ++ct) acc[ct] = (f32x4){0.f, 0.f, 0.f, 0.f};

#pragma unroll
    for (int kci = 0; kci < 4; ++kci) {
        const int kc = kci * 32;
        // A frag: X[arow][kc + koff0 + 0..7] fp32 -> bf16 (same (g,j)->k bijection as B)
        float4 v0 = make_float4(0.f, 0.f, 0.f, 0.f), v1 = v0;
        if (aok) {
            const float* xp = &X[(size_t)arow * DIM + kc + koff0];
            v0 = *(const float4*)xp;
            v1 = *(const float4*)(xp + 4);
        }
        short8v a;
        a[0] = (short)f2bf(v0.x); a[1] = (short)f2bf(v0.y);
        a[2] = (short)f2bf(v0.z); a[3] = (short)f2bf(v0.w);
        a[4] = (short)f2bf(v1.x); a[5] = (short)f2bf(v1.y);
        a[6] = (short)f2bf(v1.z); a[7] = (short)f2bf(v1.w);
#pragma unroll
        for (int ct = 0; ct < 8; ++ct) {
            short8v b = *(const short8v*)&wt[(size_t)(ct * 16 + lm) * DIM + kc + koff0];
            acc[ct] = __builtin_amdgcn_mfma_f32_16x16x32_bf16(a, b, acc[ct], 0, 0, 0);
        }
    }

    // D: row = m0 + lg*4 + r, col = ct*16 + lm
#pragma unroll
    for (int r = 0; r < 4; ++r) {
        int row = m0 + lg * 4 + r;
        if (row < N_NODES) {
            ushort* hp = &h16[(size_t)row * DIM + lm];
#pragma unroll
            for (int ct = 0; ct < 8; ++ct) hp[ct * 16] = f2bf(acc[ct][r]);
        }
    }
}

// ---------------- level-2: per-bucket LDS binning -> slot rows + deg (all streaming) ------
__launch_bounds__(256)
__global__ void bin_kernel(const int* __restrict__ gcntp, const int* __restrict__ gbkt,
                           const int* __restrict__ ocnt, const int* __restrict__ obkt,
                           ushort* __restrict__ slot, int* __restrict__ deg) {
    __shared__ __align__(16) ushort lslot[256 * CAP];   // 32 KB
    __shared__ int ldeg[256];
    const int t = threadIdx.x;
    const int b = blockIdx.x;
    ldeg[t] = 0;
    __syncthreads();

    const int cnt = min(gcntp[b * 16], GCAP);
    const int* bp = &gbkt[b * GCAP];
    for (int i = t; i < cnt; i += 256) {
        unsigned en = (unsigned)bp[i];
        int dlow = (en >> 16) & 255;
        int pos = atomicAdd(&ldeg[dlow], 1);
        if (pos < CAP) lslot[dlow * CAP + pos] = (ushort)(en & 0xFFFFu);
    }
    const int oc = min(*ocnt, OCAP);
    for (int i = t; i < oc; i += 256) {
        unsigned en = (unsigned)obkt[i];
        if ((int)(en >> 24) == b) {
            int dlow = (en >> 16) & 255;
            int pos = atomicAdd(&ldeg[dlow], 1);
            if (pos < CAP) lslot[dlow * CAP + pos] = (ushort)(en & 0xFFFFu);
        }
    }
    __syncthreads();

    const int node = b * 256 + t;
    if (node < N_NODES) deg[node] = ldeg[t];
    // stream 32 KB of slot rows (tails beyond ldeg are never read)
    const uint4* ls4 = (const uint4*)lslot;
    uint4* gs4 = (uint4*)&slot[(size_t)b * 256 * CAP];
#pragma unroll
    for (int k = 0; k < 8; ++k) gs4[k * 256 + t] = ls4[k * 256 + t];
}

// ---------------- pull: out[n] = dis_n*(sum_e dis_s*h[s] + dis_n*h[n]) + b ----------
// One wave per node; quarter-wave (16 lanes x 16B) per edge -> 4 edges in flight.
__launch_bounds__(256)
__global__ void pull_kernel(const int* __restrict__ deg, const ushort* __restrict__ slot,
                            const ushort* __restrict__ h16,
                            const float* __restrict__ b, float* __restrict__ out) {
    const int tid  = threadIdx.x;
    const int lane = tid & 63;
    const int g    = lane >> 4;     // edge slot group 0..3
    const int c    = lane & 15;     // col slot: bf16 cols c*8 .. c*8+7
    const int n    = blockIdx.x * 4 + (tid >> 6);
    if (n >= N_NODES) return;

    const int dn_i = deg[n];
    const int end  = min(dn_i, CAP);
    const ushort* sp = &slot[(size_t)n * CAP];

    float ac[8];
#pragma unroll
    for (int j = 0; j < 8; ++j) ac[j] = 0.f;

    int e = g;
    while (e + 4 < end) {           // 2 edges per group per iter
        int s0 = sp[e];
        int s1 = sp[e + 4];
        float d0 = rsqrtf(1.0f + (float)deg[s0]);
        float d1 = rsqrtf(1.0f + (float)deg[s1]);
        uint4 u0 = *(const uint4*)&h16[(size_t)s0 * DIM + c * 8];
        uint4 u1 = *(const uint4*)&h16[(size_t)s1 * DIM + c * 8];
        const unsigned w0[4] = {u0.x, u0.y, u0.z, u0.w};
        const unsigned w1[4] = {u1.x, u1.y, u1.z, u1.w};
#pragma unroll
        for (int p = 0; p < 4; ++p) {
            ac[2*p]   += d0 * __uint_as_float(w0[p] << 16)
                       + d1 * __uint_as_float(w1[p] << 16);
            ac[2*p+1] += d0 * __uint_as_float(w0[p] & 0xFFFF0000u)
                       + d1 * __uint_as_float(w1[p] & 0xFFFF0000u);
        }
        e += 8;
    }
    while (e < end) {
        int s = sp[e];
        float d = rsqrtf(1.0f + (float)deg[s]);
        uint4 u = *(const uint4*)&h16[(size_t)s * DIM + c * 8];
        const unsigned w[4] = {u.x, u.y, u.z, u.w};
#pragma unroll
        for (int p = 0; p < 4; ++p) {
            ac[2*p]   += d * __uint_as_float(w[p] << 16);
            ac[2*p+1] += d * __uint_as_float(w[p] & 0xFFFF0000u);
        }
        e += 4;
    }

    // combine the 4 edge-slot partials (same cols in every group)
#pragma unroll
    for (int j = 0; j < 8; ++j) {
        ac[j] += __shfl_xor(ac[j], 16, 64);
        ac[j] += __shfl_xor(ac[j], 32, 64);
    }

    if (g == 0) {
        const float dn = rsqrtf(1.0f + (float)dn_i);
        uint4 us = *(const uint4*)&h16[(size_t)n * DIM + c * 8];   // self row (bf16)
        const unsigned ws[4] = {us.x, us.y, us.z, us.w};
        float r[8];
#pragma unroll
        for (int p = 0; p < 4; ++p) {
            r[2*p]   = ac[2*p]   + dn * __uint_as_float(ws[p] << 16);
            r[2*p+1] = ac[2*p+1] + dn * __uint_as_float(ws[p] & 0xFFFF0000u);
        }
        float* op = &out[(size_t)n * DIM + c * 8];
        const float* bp = &b[c * 8];
        float4 o0, o1;
        o0.x = dn * r[0] + bp[0]; o0.y = dn * r[1] + bp[1];
        o0.z = dn * r[2] + bp[2]; o0.w = dn * r[3] + bp[3];
        o1.x = dn * r[4] + bp[4]; o1.y = dn * r[5] + bp[5];
        o1.z = dn * r[6] + bp[6]; o1.w = dn * r[7] + bp[7];
        *(float4*)op = o0;
        *(float4*)(op + 4) = o1;
    }
}

extern "C" void kernel_launch(void* const* d_in, const int* in_sizes, int n_in,
                              void* d_out, int out_size, void* d_ws, size_t ws_size,
                              hipStream_t stream) {
    const float* W_embed = (const float*)d_in[0];
    const float* W_gcn   = (const float*)d_in[1];
    const float* b_gcn   = (const float*)d_in[2];
    const int*   edges   = (const int*)d_in[3];
    const int E = in_sizes[3] / 2;
    const int* src = edges;
    const int* dst = edges + E;

    float* out = (float*)d_out;
    char*  ws  = (char*)d_ws;
    int*    gcntp = (int*)ws;                    // NB*16 ints, line-padded (12.5 KB) @ 0
    int*    ocnt  = (int*)(ws + 0x4000);         // 1 int                  @ 16 KB
    int*    obkt  = (int*)(ws + 0x8000);         // OCAP ints (32 KB)      @ 32 KB
    ushort* wt    = (ushort*)(ws + 0x10000);     // 128x128 bf16 (32 KB)   @ 64 KB
    int*    gbkt  = (int*)(ws + 0x20000);        // NB*GCAP ints (2.81 MB) @ 128 KB
    ushort* slot  = (ushort*)(ws + 0x300000);    // NB*256*CAP ushort (6.4MB) @ 3 MB
    int*    deg   = (int*)(ws + 0xA00000);       // N ints (200 KB)        @ 10 MB
    ushort* h16   = (ushort*)(ws + 0xC00000);    // N*D bf16 (12.8 MB)     @ 12 MB

    prep_kernel<<<17, 256, 0, stream>>>(gcntp, ocnt, W_gcn, wt);
    gemm_fill_kernel<<<GEMM_BLOCKS + FILLB, 256, 0, stream>>>(
        W_embed, wt, h16, src, dst, E, gcntp, gbkt, ocnt, obkt);
    bin_kernel<<<NB, 256, 0, stream>>>(gcntp, gbkt, ocnt, obkt, slot, deg);
    pull_kernel<<<(N_NODES + 3) / 4, 256, 0, stream>>>(deg, slot, h16, b_gcn, out);
}

// Round 13
// 72.479 us; speedup vs baseline: 2.1807x; 1.0078x over previous
//
#include <hip/hip_runtime.h>

#define N_NODES 50001
#define DIM 128
#define GEMM_BLOCKS 782                // ceil(N_NODES / 64): 4 waves x 16 rows per block
#define CAP 64                         // slot capacity per node
#define NB 196                         // buckets = dst>>8
#define FILLB 293                      // fill blocks
#define EPB 2048                       // edges per fill block (293*2048 >= 600000)
#define BCAP 40                        // per-(block,bucket) LDS capacity (mean 10.45)
#define GCAPR 640                      // per-(bucket,replica) capacity (mean 383, +13 sigma)
#define OCAP 8192                      // overflow list capacity

typedef __attribute__((ext_vector_type(8))) short short8v;   // 8 bf16 (MFMA A/B frag)
typedef __attribute__((ext_vector_type(4))) float f32x4;     // MFMA C/D frag

__device__ __forceinline__ ushort f2bf(float f) {
    unsigned u = __float_as_uint(f);
    unsigned r = (u + 0x7FFF + ((u >> 16) & 1)) >> 16;   // round-to-nearest-even
    return (ushort)r;
}

// ---------------- prep: [zero counters | transpose W (fp32) -> wt (bf16 [n][k])] ----------
__global__ void prep_kernel(int* __restrict__ gcntp, int* __restrict__ ocnt,
                            const float* __restrict__ Wg, ushort* __restrict__ wt) {
    __shared__ float tile[32][36];
    const int t = threadIdx.x;
    if (blockIdx.x == 0) {
        for (int i = t; i < NB * 8 * 16; i += 256) gcntp[i] = 0;
        if (t == 0) *ocnt = 0;
        return;
    }
    const int b2 = blockIdx.x - 1;        // 0..15
    const int bk = b2 >> 2;               // k-tile
    const int bn = b2 & 3;                // n-tile
    {
        int k = bk * 32 + (t >> 3);
        int n = bn * 32 + (t & 7) * 4;
        float4 v = *(const float4*)&Wg[(size_t)k * DIM + n];
        tile[t >> 3][(t & 7) * 4 + 0] = v.x;
        tile[t >> 3][(t & 7) * 4 + 1] = v.y;
        tile[t >> 3][(t & 7) * 4 + 2] = v.z;
        tile[t >> 3][(t & 7) * 4 + 3] = v.w;
    }
    __syncthreads();
    {
        int n = bn * 32 + (t >> 3);
        int k = bk * 32 + (t & 7) * 4;
        ushort4 w4;
        w4.x = f2bf(tile[(t & 7) * 4 + 0][t >> 3]);
        w4.y = f2bf(tile[(t & 7) * 4 + 1][t >> 3]);
        w4.z = f2bf(tile[(t & 7) * 4 + 2][t >> 3]);
        w4.w = f2bf(tile[(t & 7) * 4 + 3][t >> 3]);
        *(ushort4*)&wt[(size_t)n * DIM + k] = w4;
    }
}

// -------- fused: [MFMA gemm (first) | level-1: LDS bin 2048 edges -> replica-run flush] ---
// flush counters/lists are per (bucket, replica r=bid&7 ~ XCD): ~37 atomics per line,
// mostly XCD-local. entry = src | (dst&255)<<16 (| bucket<<24 in overflow list).
__launch_bounds__(256)
__global__ void gemm_fill_kernel(const float* __restrict__ X, const ushort* __restrict__ wt,
                                 ushort* __restrict__ h16,
                                 const int* __restrict__ src, const int* __restrict__ dst,
                                 int E, int* __restrict__ gcntp, int* __restrict__ gbkt,
                                 int* __restrict__ ocnt, int* __restrict__ obkt) {
    __shared__ int lcnt[NB];
    __shared__ int lbkt[NB * BCAP];      // ~31 KB
    const int bid = blockIdx.x;
    const int t   = threadIdx.x;
    if (bid >= GEMM_BLOCKS) {
        const int fid = bid - GEMM_BLOCKS;
        const int r   = bid & 7;         // ~XCD id (round-robin dispatch heuristic)
        for (int i = t; i < NB; i += 256) lcnt[i] = 0;
        __syncthreads();
        const int e0 = fid * EPB;
        const int e1 = min(e0 + EPB, E);
        for (int e = e0 + t; e < e1; e += 256) {
            int d = dst[e];
            int s = src[e];
            int b = d >> 8;
            unsigned en = (unsigned)s | ((unsigned)(d & 255) << 16);
            int pos = atomicAdd(&lcnt[b], 1);
            if (pos < BCAP) lbkt[b * BCAP + pos] = (int)en;
            else {
                int op = atomicAdd(ocnt, 1);
                if (op < OCAP) obkt[op] = (int)(en | ((unsigned)b << 24));
            }
        }
        __syncthreads();
        if (t < NB) {
            int c = min(lcnt[t], BCAP);
            if (c > 0) {
                int gpos = atomicAdd(&gcntp[(t * 8 + r) * 16], c);
                int* gp = &gbkt[(size_t)(t * 8 + r) * GCAPR];
                for (int i = 0; i < c; ++i) {
                    int g = gpos + i;
                    if (g < GCAPR) gp[g] = lbkt[t * BCAP + i];
                    else {
                        int op = atomicAdd(ocnt, 1);
                        if (op < OCAP)
                            obkt[op] = (int)((unsigned)lbkt[t * BCAP + i] | ((unsigned)t << 24));
                    }
                }
            }
        }
        return;
    }
    const int vb   = bid;
    const int l    = t & 63;
    const int wave = t >> 6;
    const int m0   = vb * 64 + wave * 16;
    const int lm   = l & 15;          // A row / D col index
    const int lg   = l >> 4;          // k-group

    const int arow  = m0 + lm;
    const bool aok  = (arow > 0) && (arow < N_NODES);   // row 0 forced to zero
    const int koff0 = lg * 8;

    f32x4 acc[8];
#pragma unroll
    for (int ct = 0; ct < 8; ++ct) acc[ct] = (f32x4){0.f, 0.f, 0.f, 0.f};

#pragma unroll
    for (int kci = 0; kci < 4; ++kci) {
        const int kc = kci * 32;
        // A frag: X[arow][kc + koff0 + 0..7] fp32 -> bf16 (same (g,j)->k bijection as B)
        float4 v0 = make_float4(0.f, 0.f, 0.f, 0.f), v1 = v0;
        if (aok) {
            const float* xp = &X[(size_t)arow * DIM + kc + koff0];
            v0 = *(const float4*)xp;
            v1 = *(const float4*)(xp + 4);
        }
        short8v a;
        a[0] = (short)f2bf(v0.x); a[1] = (short)f2bf(v0.y);
        a[2] = (short)f2bf(v0.z); a[3] = (short)f2bf(v0.w);
        a[4] = (short)f2bf(v1.x); a[5] = (short)f2bf(v1.y);
        a[6] = (short)f2bf(v1.z); a[7] = (short)f2bf(v1.w);
#pragma unroll
        for (int ct = 0; ct < 8; ++ct) {
            short8v b = *(const short8v*)&wt[(size_t)(ct * 16 + lm) * DIM + kc + koff0];
            acc[ct] = __builtin_amdgcn_mfma_f32_16x16x32_bf16(a, b, acc[ct], 0, 0, 0);
        }
    }

    // D: row = m0 + lg*4 + r, col = ct*16 + lm
#pragma unroll
    for (int r = 0; r < 4; ++r) {
        int row = m0 + lg * 4 + r;
        if (row < N_NODES) {
            ushort* hp = &h16[(size_t)row * DIM + lm];
#pragma unroll
            for (int ct = 0; ct < 8; ++ct) hp[ct * 16] = f2bf(acc[ct][r]);
        }
    }
}

// ---------------- level-2: per-bucket LDS binning -> slot rows + deg (all streaming) ------
__launch_bounds__(256)
__global__ void bin_kernel(const int* __restrict__ gcntp, const int* __restrict__ gbkt,
                           const int* __restrict__ ocnt, const int* __restrict__ obkt,
                           ushort* __restrict__ slot, int* __restrict__ deg) {
    __shared__ __align__(16) ushort lslot[256 * CAP];   // 32 KB
    __shared__ int ldeg[256];
    const int t = threadIdx.x;
    const int b = blockIdx.x;
    ldeg[t] = 0;
    __syncthreads();

    for (int r = 0; r < 8; ++r) {
        const int cnt = min(gcntp[(b * 8 + r) * 16], GCAPR);
        const int* bp = &gbkt[(size_t)(b * 8 + r) * GCAPR];
        for (int i = t; i < cnt; i += 256) {
            unsigned en = (unsigned)bp[i];
            int dlow = (en >> 16) & 255;
            int pos = atomicAdd(&ldeg[dlow], 1);
            if (pos < CAP) lslot[dlow * CAP + pos] = (ushort)(en & 0xFFFFu);
        }
    }
    const int oc = min(*ocnt, OCAP);
    for (int i = t; i < oc; i += 256) {
        unsigned en = (unsigned)obkt[i];
        if ((int)(en >> 24) == b) {
            int dlow = (en >> 16) & 255;
            int pos = atomicAdd(&ldeg[dlow], 1);
            if (pos < CAP) lslot[dlow * CAP + pos] = (ushort)(en & 0xFFFFu);
        }
    }
    __syncthreads();

    const int node = b * 256 + t;
    if (node < N_NODES) deg[node] = ldeg[t];
    // stream 32 KB of slot rows (tails beyond ldeg are never read)
    const uint4* ls4 = (const uint4*)lslot;
    uint4* gs4 = (uint4*)&slot[(size_t)b * 256 * CAP];
#pragma unroll
    for (int k = 0; k < 8; ++k) gs4[k * 256 + t] = ls4[k * 256 + t];
}

// ---------------- pull: out[n] = dis_n*(sum_e dis_s*h[s] + dis_n*h[n]) + b ----------
// One wave per node; quarter-wave (16 lanes x 16B) per edge -> 4 edges in flight.
__launch_bounds__(256)
__global__ void pull_kernel(const int* __restrict__ deg, const ushort* __restrict__ slot,
                            const ushort* __restrict__ h16,
                            const float* __restrict__ b, float* __restrict__ out) {
    const int tid  = threadIdx.x;
    const int lane = tid & 63;
    const int g    = lane >> 4;     // edge slot group 0..3
    const int c    = lane & 15;     // col slot: bf16 cols c*8 .. c*8+7
    const int n    = blockIdx.x * 4 + (tid >> 6);
    if (n >= N_NODES) return;

    const int dn_i = deg[n];
    const int end  = min(dn_i, CAP);
    const ushort* sp = &slot[(size_t)n * CAP];

    float ac[8];
#pragma unroll
    for (int j = 0; j < 8; ++j) ac[j] = 0.f;

    int e = g;
    while (e + 4 < end) {           // 2 edges per group per iter
        int s0 = sp[e];
        int s1 = sp[e + 4];
        float d0 = rsqrtf(1.0f + (float)deg[s0]);
        float d1 = rsqrtf(1.0f + (float)deg[s1]);
        uint4 u0 = *(const uint4*)&h16[(size_t)s0 * DIM + c * 8];
        uint4 u1 = *(const uint4*)&h16[(size_t)s1 * DIM + c * 8];
        const unsigned w0[4] = {u0.x, u0.y, u0.z, u0.w};
        const unsigned w1[4] = {u1.x, u1.y, u1.z, u1.w};
#pragma unroll
        for (int p = 0; p < 4; ++p) {
            ac[2*p]   += d0 * __uint_as_float(w0[p] << 16)
                       + d1 * __uint_as_float(w1[p] << 16);
            ac[2*p+1] += d0 * __uint_as_float(w0[p] & 0xFFFF0000u)
                       + d1 * __uint_as_float(w1[p] & 0xFFFF0000u);
        }
        e += 8;
    }
    while (e < end) {
        int s = sp[e];
        float d = rsqrtf(1.0f + (float)deg[s]);
        uint4 u = *(const uint4*)&h16[(size_t)s * DIM + c * 8];
        const unsigned w[4] = {u.x, u.y, u.z, u.w};
#pragma unroll
        for (int p = 0; p < 4; ++p) {
            ac[2*p]   += d * __uint_as_float(w[p] << 16);
            ac[2*p+1] += d * __uint_as_float(w[p] & 0xFFFF0000u);
        }
        e += 4;
    }

    // combine the 4 edge-slot partials (same cols in every group)
#pragma unroll
    for (int j = 0; j < 8; ++j) {
        ac[j] += __shfl_xor(ac[j], 16, 64);
        ac[j] += __shfl_xor(ac[j], 32, 64);
    }

    if (g == 0) {
        const float dn = rsqrtf(1.0f + (float)dn_i);
        uint4 us = *(const uint4*)&h16[(size_t)n * DIM + c * 8];   // self row (bf16)
        const unsigned ws[4] = {us.x, us.y, us.z, us.w};
        float r[8];
#pragma unroll
        for (int p = 0; p < 4; ++p) {
            r[2*p]   = ac[2*p]   + dn * __uint_as_float(ws[p] << 16);
            r[2*p+1] = ac[2*p+1] + dn * __uint_as_float(ws[p] & 0xFFFF0000u);
        }
        float* op = &out[(size_t)n * DIM + c * 8];
        const float* bp = &b[c * 8];
        float4 o0, o1;
        o0.x = dn * r[0] + bp[0]; o0.y = dn * r[1] + bp[1];
        o0.z = dn * r[2] + bp[2]; o0.w = dn * r[3] + bp[3];
        o1.x = dn * r[4] + bp[4]; o1.y = dn * r[5] + bp[5];
        o1.z = dn * r[6] + bp[6]; o1.w = dn * r[7] + bp[7];
        *(float4*)op = o0;
        *(float4*)(op + 4) = o1;
    }
}

extern "C" void kernel_launch(void* const* d_in, const int* in_sizes, int n_in,
                              void* d_out, int out_size, void* d_ws, size_t ws_size,
                              hipStream_t stream) {
    const float* W_embed = (const float*)d_in[0];
    const float* W_gcn   = (const float*)d_in[1];
    const float* b_gcn   = (const float*)d_in[2];
    const int*   edges   = (const int*)d_in[3];
    const int E = in_sizes[3] / 2;
    const int* src = edges;
    const int* dst = edges + E;

    float* out = (float*)d_out;
    char*  ws  = (char*)d_ws;
    int*    gcntp = (int*)ws;                    // NB*8*16 ints, line-padded (98 KB) @ 0
    int*    ocnt  = (int*)(ws + 0x19000);        // 1 int                  @ 100 KB
    int*    obkt  = (int*)(ws + 0x20000);        // OCAP ints (32 KB)      @ 128 KB
    ushort* wt    = (ushort*)(ws + 0x28000);     // 128x128 bf16 (32 KB)   @ 160 KB
    int*    gbkt  = (int*)(ws + 0x30000);        // NB*8*GCAPR ints (4 MB) @ 192 KB
    ushort* slot  = (ushort*)(ws + 0x500000);    // NB*256*CAP ushort (6.4MB) @ 5 MB
    int*    deg   = (int*)(ws + 0xC00000);       // N ints (200 KB)        @ 12 MB
    ushort* h16   = (ushort*)(ws + 0xD00000);    // N*D bf16 (12.8 MB)     @ 13 MB

    prep_kernel<<<17, 256, 0, stream>>>(gcntp, ocnt, W_gcn, wt);
    gemm_fill_kernel<<<GEMM_BLOCKS + FILLB, 256, 0, stream>>>(
        W_embed, wt, h16, src, dst, E, gcntp, gbkt, ocnt, obkt);
    bin_kernel<<<NB, 256, 0, stream>>>(gcntp, gbkt, ocnt, obkt, slot, deg);
    pull_kernel<<<(N_NODES + 3) / 4, 256, 0, stream>>>(deg, slot, h16, b_gcn, out);
}